// Round 2
// baseline (585.866 us; speedup 1.0000x reference)
//
#include <hip/hip_runtime.h>
#include <stdint.h>

// AttentionReadout: G=1024 x N=64, D=512, H=8, hd=64. fp32 I/O, bf16 MFMA.
// v7: 16-wave (1024-thr) blocks, wave PAIR per head split by n-strips.
// v6 lesson (rocprof): 2 waves/SIMD -> all pipes <20% busy, latency-bound.
// Wave (h,q2): q2 owns n-strips {2q2,2q2+1} for QKV/scores-rows/softmax/P,
// and d-tiles {2q2,2q2+1} for PV/gate/ctx. Partner K-frags exchanged through
// xs (dead after QKV). 6 syncthreads. u/c0 folded in (finalize_u removed);
// u-partials folded into convert_weights (5 launches -> 3).
// (Round-1 resubmit: prior bench was a container-acquisition failure; audit
// found no correctness/deadlock defect. Source unchanged.)

typedef __attribute__((ext_vector_type(8))) short short8;   // 8 bf16
typedef __attribute__((ext_vector_type(4))) float f32x4;    // MFMA C/D frag

#define D_ 512

// ---- ws layout (bytes) ----
#define WQKV_OFF   0u          // 1536*512 bf16 = 1572864
#define WO_OFF     1572864u    // 512*512 bf16  = 524288
#define UPART_OFF  2097152u    // 16*512 f32    = 32768
#define SG_OFF     2132032u    // 1024 f32      = 4096
#define WCTX_OFF   2136128u    // 1024*512 bf16 = 1 MB (16B aligned)

__device__ __forceinline__ unsigned short f2bf(float f) {
    union { float f; unsigned int u; } t; t.f = f;
    unsigned int u = t.u;
    return (unsigned short)((u + 0x7FFFu + ((u >> 16) & 1u)) >> 16);  // RNE
}
__device__ __forceinline__ unsigned pack2(float a, float b) {
    return (unsigned)f2bf(a) | ((unsigned)f2bf(b) << 16);
}

// ---- pre-pass: wqkv + wo fp32 -> bf16; blocks >=1024 compute u partials ----
__global__ __launch_bounds__(256)
void convert_weights(const float* __restrict__ wqkv, const float* __restrict__ wo,
                     unsigned short* __restrict__ wbf,
                     const float* __restrict__ gw, float* __restrict__ upart) {
    if (blockIdx.x >= 1024) {   // u-partial role: upart[b][d] = sum_{e in b*32..} wo[e][d]*gw[e]
        const int b = blockIdx.x - 1024;
        const int t = threadIdx.x;
        float a0 = 0.f, a1 = 0.f;
        #pragma unroll 4
        for (int e = b * 32; e < b * 32 + 32; ++e) {
            const float ge = gw[e];
            a0 += wo[(size_t)e * 512 + t]       * ge;
            a1 += wo[(size_t)e * 512 + t + 256] * ge;
        }
        upart[b * 512 + t] = a0; upart[b * 512 + t + 256] = a1;
        return;
    }
    const int i4 = blockIdx.x * 256 + threadIdx.x;          // 262144 float4 total
    float4 v;
    if (i4 < 196608) v = *(const float4*)(wqkv + (size_t)i4 * 4);
    else             v = *(const float4*)(wo   + (size_t)(i4 - 196608) * 4);
    uint2 p; p.x = pack2(v.x, v.y); p.y = pack2(v.z, v.w);
    *(uint2*)(wbf + (size_t)i4 * 4) = p;
}

union U8 { unsigned u[4]; short8 s; };

// ---- main: per-graph, wave-PAIR-per-head (n-strip split), 16 waves ----
__global__ __launch_bounds__(1024, 4)
void attn_ctx_kernel(const float* __restrict__ x,             // [65536,512] f32
                     const unsigned short* __restrict__ wqkv, // [1536,512] bf16
                     const float* __restrict__ bqkv,          // [1536] f32
                     const float* __restrict__ upart,         // [16,512] f32
                     const float* __restrict__ bo,            // [512] f32
                     const float* __restrict__ gw,            // [512] f32
                     const float* __restrict__ gb,            // [1] f32
                     unsigned short* __restrict__ wctx_ws,    // [1024,512] bf16
                     float* __restrict__ sumgate)             // [1024] f32
{
    __shared__ __align__(16) unsigned short xs[64][520];      // 66560 B; reused as kB exchange
    __shared__ __align__(16) unsigned short scr[8][64][72];   // 73728 B; per-head vT then P
    __shared__ float logitp[16][64];                          // 4096 B
    __shared__ float u_s[512];                                // 2048 B
    __shared__ float c0_s;
    __shared__ float gatev[64];                               // 256 B
    // total ~146.7 KB -> 1 block/CU, 16 waves = 4 waves/SIMD

    const int g    = blockIdx.x;
    const int tid  = threadIdx.x;
    const int w    = tid >> 6;      // 16 waves
    const int lane = tid & 63;
    const int l15  = lane & 15;
    const int quad = lane >> 4;
    const int h    = w >> 1;        // head = wave pair
    const int q2   = w & 1;         // which half of the pair

    // ---- stage x once: fp32 -> bf16 LDS; also u = sum(upart), c0 ----
    #pragma unroll
    for (int i = 0; i < 8; ++i) {
        int idx = tid + i * 1024;
        int row = idx >> 7;
        int c4  = idx & 127;
        float4 v = *(const float4*)(x + ((size_t)(g*64 + row))*512 + c4*4);
        uint2 p; p.x = pack2(v.x, v.y); p.y = pack2(v.z, v.w);
        *(uint2*)(&xs[row][c4*4]) = p;
    }
    if (tid < 512) {
        float s = 0.f;
        #pragma unroll
        for (int b = 0; b < 16; ++b) s += upart[b*512 + tid];
        u_s[tid] = s;
    } else if (tid < 576) {          // wave 8 whole: c0 = bo.gw + gb
        const int j = tid - 512;
        float s = 0.f;
        #pragma unroll
        for (int i = 0; i < 8; ++i) s += bo[j*8 + i] * gw[j*8 + i];
        s += __shfl_xor(s, 1);  s += __shfl_xor(s, 2);  s += __shfl_xor(s, 4);
        s += __shfl_xor(s, 8);  s += __shfl_xor(s, 16); s += __shfl_xor(s, 32);
        if (j == 0) c0_s = s + gb[0];
    }
    __syncthreads();   // (1)

    unsigned short (*S)[72] = scr[h];   // shared by the wave pair

    // ======== QKV for head h, own n-strips {2q2, 2q2+1} (K=512) ========
    U8 qA[2][2], kB[2][2];   // [local n-strip][ks2]
    #pragma unroll
    for (int dt = 0; dt < 4; ++dt) {
        f32x4 aq[2], ak[2], av[2];
        #pragma unroll
        for (int n = 0; n < 2; ++n) {
            aq[n] = (f32x4){0.f,0.f,0.f,0.f};
            ak[n] = (f32x4){0.f,0.f,0.f,0.f};
            av[n] = (f32x4){0.f,0.f,0.f,0.f};
        }
        const unsigned short* wq = wqkv + (size_t)(          h*64 + dt*16 + l15) * 512;
        const unsigned short* wk = wqkv + (size_t)( 512 +    h*64 + dt*16 + l15) * 512;
        const unsigned short* wv = wqkv + (size_t)(1024 +    h*64 + dt*16 + l15) * 512;
        #pragma unroll 4
        for (int ks = 0; ks < 16; ++ks) {
            const int col = ks*32 + quad*8;
            short8 a0 = *(const short8*)(wq + col);
            short8 a1 = *(const short8*)(wk + col);
            short8 a2 = *(const short8*)(wv + col);
            #pragma unroll
            for (int n = 0; n < 2; ++n) {
                short8 b = *(const short8*)(&xs[(q2*2 + n)*16 + l15][col]);
                aq[n] = __builtin_amdgcn_mfma_f32_16x16x32_bf16(a0, b, aq[n], 0,0,0);
                ak[n] = __builtin_amdgcn_mfma_f32_16x16x32_bf16(a1, b, ak[n], 0,0,0);
                av[n] = __builtin_amdgcn_mfma_f32_16x16x32_bf16(a2, b, av[n], 0,0,0);
            }
        }
        float bq[4], bk2[4], bv2[4];
        #pragma unroll
        for (int r = 0; r < 4; ++r) {
            bq[r]  = bqkv[          h*64 + dt*16 + quad*4 + r];
            bk2[r] = bqkv[ 512 +    h*64 + dt*16 + quad*4 + r];
            bv2[r] = bqkv[1024 +    h*64 + dt*16 + quad*4 + r];
        }
        const bool take = ((quad >> 1) == (dt & 1));
        const int  ks2  = dt >> 1;
        #pragma unroll
        for (int n = 0; n < 2; ++n) {
            const int nt = q2*2 + n;
            // q/k C-layout [d][n] -> frag [n][d] via quad shuffles (verbatim v6)
            unsigned q01 = pack2(aq[n][0]+bq[0],  aq[n][1]+bq[1]);
            unsigned q23 = pack2(aq[n][2]+bq[2],  aq[n][3]+bq[3]);
            unsigned k01 = pack2(ak[n][0]+bk2[0], ak[n][1]+bk2[1]);
            unsigned k23 = pack2(ak[n][2]+bk2[2], ak[n][3]+bk2[3]);
            #pragma unroll
            for (int j = 0; j < 4; ++j) {
                int srcl = ((quad & 1)*2 + (j >> 1))*16 + l15;
                unsigned tq = (unsigned)__shfl((int)((j & 1) ? q23 : q01), srcl);
                unsigned tk = (unsigned)__shfl((int)((j & 1) ? k23 : k01), srcl);
                if (take) { qA[n][ks2].u[j] = tq; kB[n][ks2].u[j] = tk; }
            }
            // v (+bias) -> scratch vT[d][m], own m-columns only (pair-disjoint)
            #pragma unroll
            for (int r = 0; r < 4; ++r)
                S[dt*16 + quad*4 + r][nt*16 + l15] = f2bf(av[n][r] + bv2[r]);
        }
    }

    __syncthreads();   // (2) xs b-frag reads done block-wide; scr vT complete

    // ---- extract vA for OWN d-tiles (rows [32*q2,32*q2+32), all m) ----
    U8 vA[2][2];
    #pragma unroll
    for (int dl = 0; dl < 2; ++dl)
        #pragma unroll
        for (int km = 0; km < 2; ++km)
            vA[dl][km].s = *(const short8*)(&S[(q2*2 + dl)*16 + l15][km*32 + quad*8]);

    // ---- kB exchange through xs (dead after QKV): 64 slots x 1 KB ----
    short8* exch = (short8*)(&xs[0][0]);
    #pragma unroll
    for (int n = 0; n < 2; ++n)
        #pragma unroll
        for (int ks2 = 0; ks2 < 2; ++ks2)
            exch[(((w*2) + n)*2 + ks2)*64 + lane] = kB[n][ks2].s;
    __syncthreads();   // (3)
    U8 kBo[2][2];
    #pragma unroll
    for (int n = 0; n < 2; ++n)
        #pragma unroll
        for (int ks2 = 0; ks2 < 2; ++ks2)
            kBo[n][ks2].s = exch[((((w^1)*2) + n)*2 + ks2)*64 + lane];

    // ======== scores for OWN rows: sacc[al][bl], bl local order {own0,own1,oth0,oth1} ========
    f32x4 sacc[2][4];
    #pragma unroll
    for (int al = 0; al < 2; ++al)
        #pragma unroll
        for (int bl = 0; bl < 4; ++bl) sacc[al][bl] = (f32x4){0.f,0.f,0.f,0.f};
    #pragma unroll
    for (int ks2 = 0; ks2 < 2; ++ks2)
        #pragma unroll
        for (int al = 0; al < 2; ++al) {
            #pragma unroll
            for (int n = 0; n < 2; ++n) {
                sacc[al][n]   = __builtin_amdgcn_mfma_f32_16x16x32_bf16(
                                    qA[al][ks2].s, kB[n][ks2].s,  sacc[al][n],   0,0,0);
                sacc[al][2+n] = __builtin_amdgcn_mfma_f32_16x16x32_bf16(
                                    qA[al][ks2].s, kBo[n][ks2].s, sacc[al][2+n], 0,0,0);
            }
        }

    // ======== softmax over m (rows n = (q2*2+al)*16 + quad*4 + r) ========
    #pragma unroll
    for (int al = 0; al < 2; ++al) {
        #pragma unroll
        for (int r = 0; r < 4; ++r) {
            float m0 = -1e30f;
            #pragma unroll
            for (int bl = 0; bl < 4; ++bl) { sacc[al][bl][r] *= 0.125f; m0 = fmaxf(m0, sacc[al][bl][r]); }
            m0 = fmaxf(m0, __shfl_xor(m0, 1));
            m0 = fmaxf(m0, __shfl_xor(m0, 2));
            m0 = fmaxf(m0, __shfl_xor(m0, 4));
            m0 = fmaxf(m0, __shfl_xor(m0, 8));
            float s = 0.f;
            #pragma unroll
            for (int bl = 0; bl < 4; ++bl) { float e = __expf(sacc[al][bl][r] - m0); sacc[al][bl][r] = e; s += e; }
            s += __shfl_xor(s, 1); s += __shfl_xor(s, 2); s += __shfl_xor(s, 4); s += __shfl_xor(s, 8);
            float inv = 1.0f / s;
            #pragma unroll
            for (int bl = 0; bl < 4; ++bl) sacc[al][bl][r] *= inv;
        }
    }

    // ======== P -> scratch [n][m], OWN rows only (own rows == own vT rows) ========
    #pragma unroll
    for (int al = 0; al < 2; ++al)
        #pragma unroll
        for (int bl = 0; bl < 4; ++bl) {
            const int bg = (bl < 2 ? q2*2 : 2 - q2*2) + (bl & 1);   // local->global strip
            #pragma unroll
            for (int r = 0; r < 4; ++r)
                S[(q2*2 + al)*16 + quad*4 + r][bg*16 + l15] = f2bf(sacc[al][bl][r]);
        }
    __syncthreads();   // (4) P complete from both halves

    U8 pB[4][2];
    #pragma unroll
    for (int a = 0; a < 4; ++a)
        #pragma unroll
        for (int km = 0; km < 2; ++km)
            pB[a][km].s = *(const short8*)(&S[a*16 + l15][km*32 + quad*8]);

    // ======== PV: ctxT[d][n] for own d-tiles ========
    f32x4 cacc[2][4];   // [dl][a]; lane: d = (q2*2+dl)*16+quad*4+r, n = a*16+l15
    #pragma unroll
    for (int dl = 0; dl < 2; ++dl)
        #pragma unroll
        for (int a = 0; a < 4; ++a) cacc[dl][a] = (f32x4){0.f,0.f,0.f,0.f};
    #pragma unroll
    for (int km = 0; km < 2; ++km)
        #pragma unroll
        for (int dl = 0; dl < 2; ++dl)
            #pragma unroll
            for (int a = 0; a < 4; ++a)
                cacc[dl][a] = __builtin_amdgcn_mfma_f32_16x16x32_bf16(
                                  vA[dl][km].s, pB[a][km].s, cacc[dl][a], 0,0,0);

    // ======== gate-logit partials over own d-range ========
    {
        float uv[2][4];
        #pragma unroll
        for (int dl = 0; dl < 2; ++dl)
            #pragma unroll
            for (int r = 0; r < 4; ++r)
                uv[dl][r] = u_s[h*64 + (q2*2 + dl)*16 + quad*4 + r];
        #pragma unroll
        for (int a = 0; a < 4; ++a) {
            float s = 0.f;
            #pragma unroll
            for (int dl = 0; dl < 2; ++dl)
                #pragma unroll
                for (int r = 0; r < 4; ++r)
                    s += cacc[dl][a][r] * uv[dl][r];
            s += __shfl_xor(s, 16); s += __shfl_xor(s, 32);   // sum over quads
            if (quad == 0) logitp[w][a*16 + l15] = s;
        }
    }
    __syncthreads();   // (5)

    if (tid < 64) {
        float lg = c0_s;
        #pragma unroll
        for (int ww = 0; ww < 16; ++ww) lg += logitp[ww][tid];
        float gt = 1.0f / (1.0f + __expf(-lg));
        gatev[tid] = gt;
        float s = gt;
        s += __shfl_xor(s, 1);  s += __shfl_xor(s, 2);  s += __shfl_xor(s, 4);
        s += __shfl_xor(s, 8);  s += __shfl_xor(s, 16); s += __shfl_xor(s, 32);
        if (tid == 0) sumgate[g] = s;
    }
    __syncthreads();   // (6)

    // ======== wctx[d] = sum_n gate[n] ctx[n][d] (own d-range) ========
    {
        float gv[4];
        #pragma unroll
        for (int a = 0; a < 4; ++a) gv[a] = gatev[a*16 + l15];
        #pragma unroll
        for (int dl = 0; dl < 2; ++dl) {
            float sr[4];
            #pragma unroll
            for (int r = 0; r < 4; ++r) {
                float s = cacc[dl][0][r]*gv[0] + cacc[dl][1][r]*gv[1]
                        + cacc[dl][2][r]*gv[2] + cacc[dl][3][r]*gv[3];
                s += __shfl_xor(s, 1); s += __shfl_xor(s, 2);
                s += __shfl_xor(s, 4); s += __shfl_xor(s, 8);   // sum over l15
                sr[r] = s;
            }
            if (l15 == 0) {
                uint2 pk; pk.x = pack2(sr[0], sr[1]); pk.y = pack2(sr[2], sr[3]);
                *(uint2*)(wctx_ws + (size_t)g*512 + h*64 + (q2*2 + dl)*16 + quad*4) = pk;
            }
        }
    }
}

// ---- final out-projection: 128 blocks (32 g-blocks x 4 e-quarters) ----
__global__ __launch_bounds__(256, 4)
void outproj_kernel(const unsigned short* __restrict__ wo_bf,   // [512,512] bf16
                    const unsigned short* __restrict__ wctx_bf, // [1024,512] bf16
                    const float* __restrict__ bo,               // [512] f32
                    const float* __restrict__ sumgate,          // [1024] f32
                    float* __restrict__ out)                    // [1024,512] f32
{
    const int tid  = threadIdx.x;
    const int w    = tid >> 6;
    const int lane = tid & 63;
    const int l15  = lane & 15;
    const int quad = lane >> 4;
    const int g0   = blockIdx.x * 32;
    const int e0   = blockIdx.y * 128;

    f32x4 oac[2][2];
    #pragma unroll
    for (int et = 0; et < 2; ++et)
        #pragma unroll
        for (int mt = 0; mt < 2; ++mt)
            oac[et][mt] = (f32x4){0.f,0.f,0.f,0.f};

    #pragma unroll 4
    for (int ks = 0; ks < 16; ++ks) {
        const int col = ks*32 + quad*8;
        short8 a0 = *(const short8*)(wctx_bf + (size_t)(g0 + l15)*D_      + col);
        short8 a1 = *(const short8*)(wctx_bf + (size_t)(g0 + 16 + l15)*D_ + col);
        #pragma unroll
        for (int et = 0; et < 2; ++et) {
            short8 b = *(const short8*)(wo_bf + (size_t)(e0 + w*32 + et*16 + l15)*D_ + col);
            oac[et][0] = __builtin_amdgcn_mfma_f32_16x16x32_bf16(a0, b, oac[et][0], 0,0,0);
            oac[et][1] = __builtin_amdgcn_mfma_f32_16x16x32_bf16(a1, b, oac[et][1], 0,0,0);
        }
    }
    #pragma unroll
    for (int et = 0; et < 2; ++et) {
        const int e = e0 + w*32 + et*16 + l15;
        const float bov = bo[e];
        #pragma unroll
        for (int mt = 0; mt < 2; ++mt)
            #pragma unroll
            for (int r = 0; r < 4; ++r) {
                const int gg = g0 + mt*16 + quad*4 + r;
                out[(size_t)gg*D_ + e] = oac[et][mt][r] + sumgate[gg] * bov;
            }
    }
}

extern "C" void kernel_launch(void* const* d_in, const int* in_sizes, int n_in,
                              void* d_out, int out_size, void* d_ws, size_t ws_size,
                              hipStream_t stream) {
    const float* x    = (const float*)d_in[0];
    // d_in[1] = batch (int64) — unused: graphs are equal-sized (64 nodes)
    const float* wqkv = (const float*)d_in[2];
    const float* bqkv = (const float*)d_in[3];
    const float* wo   = (const float*)d_in[4];
    const float* bo   = (const float*)d_in[5];
    const float* gw   = (const float*)d_in[6];
    const float* gb   = (const float*)d_in[7];
    float* out = (float*)d_out;

    char* ws = (char*)d_ws;
    unsigned short* wqkv_bf = (unsigned short*)(ws + WQKV_OFF);
    unsigned short* wo_bf   = (unsigned short*)(ws + WO_OFF);
    float*          upart   = (float*)(ws + UPART_OFF);
    float*          sg_ws   = (float*)(ws + SG_OFF);
    unsigned short* wctx_ws = (unsigned short*)(ws + WCTX_OFF);

    const int total = in_sizes[0] / D_;  // 65536 nodes
    const int G     = total / 64;        // 1024 graphs

    hipLaunchKernelGGL(convert_weights, dim3(1040), dim3(256), 0, stream,
                       wqkv, wo, wqkv_bf, gw, upart);
    hipLaunchKernelGGL(attn_ctx_kernel, dim3(G), dim3(1024), 0, stream,
                       x, wqkv_bf, bqkv, upart, bo, gw, gb, wctx_ws, sg_ws);
    hipLaunchKernelGGL(outproj_kernel, dim3(G/32, 4), dim3(256), 0, stream,
                       wo_bf, wctx_ws, bo, sg_ws, out);
}